// Round 11
// baseline (253.494 us; speedup 1.0000x reference)
//
#include <hip/hip_runtime.h>
#include <hip/hip_bf16.h>
#include <math.h>

#define L2E 1.44269504f
#define LN2 0.69314718f
#define TSTRIDE 68

typedef __attribute__((ext_vector_type(2))) float floatx2;

__device__ __forceinline__ float sigf(float x){ return 1.0f/(1.0f+expf(-x)); }

__device__ __forceinline__ float quad_max(float x) {
    x = fmaxf(x, __int_as_float(__builtin_amdgcn_mov_dpp(__float_as_int(x), 0xB1, 0xF, 0xF, true)));
    x = fmaxf(x, __int_as_float(__builtin_amdgcn_mov_dpp(__float_as_int(x), 0x4E, 0xF, 0xF, true)));
    return x;
}
// 8-lane (aligned consecutive group) reductions -- PURE DPP, no LDS:
// xor1 = quad_perm swap-adjacent (0xB1), xor2 = quad_perm swap-pairs (0x4E),
// quad<->quad exchange within the 8-lane half-row = row_half_mirror (0x141).
__device__ __forceinline__ float oct_max(float x) {
    x = fmaxf(x, __int_as_float(__builtin_amdgcn_mov_dpp(__float_as_int(x), 0xB1, 0xF, 0xF, true)));
    x = fmaxf(x, __int_as_float(__builtin_amdgcn_mov_dpp(__float_as_int(x), 0x4E, 0xF, 0xF, true)));
    x = fmaxf(x, __int_as_float(__builtin_amdgcn_mov_dpp(__float_as_int(x), 0x141, 0xF, 0xF, true)));
    return x;
}
__device__ __forceinline__ float oct_sum(float x) {
    x += __int_as_float(__builtin_amdgcn_mov_dpp(__float_as_int(x), 0xB1, 0xF, 0xF, true));
    x += __int_as_float(__builtin_amdgcn_mov_dpp(__float_as_int(x), 0x4E, 0xF, 0xF, true));
    x += __int_as_float(__builtin_amdgcn_mov_dpp(__float_as_int(x), 0x141, 0xF, 0xF, true));
    return x;
}

// ---------------------------------------------------------------- prep: embed + bias + coalesced fp8 pack
__global__ __launch_bounds__(256) void prep_all(const float* __restrict__ Whh_f, const float* __restrict__ Whh_b,
                             const float* __restrict__ bih_f, const float* __restrict__ bhh_f,
                             const float* __restrict__ bih_b, const float* __restrict__ bhh_b,
                             uint4* __restrict__ qWf, uint4* __restrict__ qWb,
                             float* __restrict__ scf, float* __restrict__ scb,
                             float* __restrict__ biasf, float* __restrict__ biasb,
                             const int* __restrict__ sents, const float* __restrict__ mask,
                             const float* __restrict__ emb, float* __restrict__ embeds,
                             float* __restrict__ out) {
    int tid = threadIdx.x;
    if (blockIdx.x < 512) {
        int bl = blockIdx.x;
        const int*   srow = sents + bl*32;
        const float* mrow = mask  + bl*32;
        float acc = 0.0f, el = 0.0f;
        for (int w = 0; w < 32; ++w) {
            float m = mrow[w];
            el  += m;
            acc += emb[(size_t)srow[w]*256 + tid] * m;
        }
        float den = el + (el == 0.0f ? 1.0f : 0.0f);
        embeds[bl*256 + tid] = acc / den;
        if (bl == 0)      { for (int q = tid; q < 1024; q += 256) biasf[q] = bih_f[q] + bhh_f[q]; }
        else if (bl == 1) { for (int q = tid; q < 1024; q += 256) biasb[q] = bih_b[q] + bhh_b[q]; }
        else if (bl == 2 && tid == 0) out[0] = 0.0f;
    } else {
        int pb  = blockIdx.x - 512;      // 0..127
        int dir = pb >> 6;
        int cg  = pb & 63;               // cell group of 4
        const float* W = dir ? Whh_b : Whh_f;
        uint4* qW = dir ? qWb : qWf;
        float* sc = dir ? scb : scf;
        __shared__ float Wl[16][260];    // 16 rows (4 gates x 4 cells), padded
        __shared__ float sL[16];         // row scales [g*4+jj]
        #pragma unroll
        for (int lr = 0; lr < 16; ++lr) {
            int g = lr >> 2, jj = lr & 3;
            int rowid = g*256 + cg*4 + jj;
            Wl[lr][tid] = W[(size_t)rowid*256 + tid];
        }
        __syncthreads();
        if (tid < 64) {
            int lr = tid >> 2, sub = tid & 3;
            float mx = 0.0f;
            for (int m = 0; m < 64; ++m) mx = fmaxf(mx, fabsf(Wl[lr][sub*64 + m]));
            mx = quad_max(mx);
            if (sub == 0) sL[lr] = mx * (1.0f/240.0f) + 1e-30f;
        }
        __syncthreads();
        int k4 = tid >> 2, jj = tid & 3;
        float is0 = 1.0f / sL[0*4 + jj];
        float is1 = 1.0f / sL[1*4 + jj];
        float is2 = 1.0f / sL[2*4 + jj];
        float is3 = 1.0f / sL[3*4 + jj];
        uint4 q;
        unsigned int* qq = (unsigned int*)&q;
        #pragma unroll
        for (int kk = 0; kk < 4; ++kk) {
            int k = k4*4 + kk;
            int d = 0;
            d = __builtin_amdgcn_cvt_pk_fp8_f32(Wl[0*4+jj][k]*is0, Wl[1*4+jj][k]*is1, d, false);
            d = __builtin_amdgcn_cvt_pk_fp8_f32(Wl[2*4+jj][k]*is2, Wl[3*4+jj][k]*is3, d, true);
            qq[kk] = (unsigned int)d;
        }
        qW[k4*256 + cg*4 + jj] = q;
        if (tid < 16) {
            int g = tid >> 2, j2 = tid & 3;
            sc[(cg*4 + j2)*4 + g] = sL[g*4 + j2];
        }
    }
}

// ---------------------------------------------------------------- 32x32 GEMM body, 2x2 micro-tile
// Used for gemm_ih and p1/p2: many small blocks beat few big ones here --
// the 64-tile body at <=256 blocks leaves most CUs idle (1 block/CU,
// LDS-read-bound ~96cy/kc); 32-tiles give 4 blocks/CU residency.
__device__ __forceinline__ void gemm32_body(const float* __restrict__ A,
                                            const float* __restrict__ Bm,
                                            const float* __restrict__ bias,
                                            float* __restrict__ C,
                                            int N, int K, int bx, int by) {
    __shared__ __align__(16) float As[32][36];
    __shared__ __align__(16) float Bs[32][36];
    int tid = threadIdx.x;
    int tx = tid & 15, ty = tid >> 4;
    int row0 = bx * 32, col0 = by * 32;
    float acc00 = 0.f, acc01 = 0.f, acc10 = 0.f, acc11 = 0.f;
    int lr = tid >> 3;            // 0..31
    int lc = (tid & 7) * 4;       // 0..28
    for (int k0 = 0; k0 < K; k0 += 32) {
        float4 a0 = *(const float4*)(A  + (size_t)(row0+lr)*K + k0 + lc);
        float4 b0 = *(const float4*)(Bm + (size_t)(col0+lr)*K + k0 + lc);
        As[lc  ][lr] = a0.x; As[lc+1][lr] = a0.y; As[lc+2][lr] = a0.z; As[lc+3][lr] = a0.w;
        Bs[lc  ][lr] = b0.x; Bs[lc+1][lr] = b0.y; Bs[lc+2][lr] = b0.z; Bs[lc+3][lr] = b0.w;
        __syncthreads();
        #pragma unroll
        for (int kc = 0; kc < 32; ++kc) {
            float2 xa = *(const float2*)&As[kc][ty*2];
            float2 xb = *(const float2*)&Bs[kc][tx*2];
            acc00 = fmaf(xa.x, xb.x, acc00);
            acc01 = fmaf(xa.x, xb.y, acc01);
            acc10 = fmaf(xa.y, xb.x, acc10);
            acc11 = fmaf(xa.y, xb.y, acc11);
        }
        __syncthreads();
    }
    float2 bv = *(const float2*)&bias[col0 + tx*2];
    float2 o0; o0.x = acc00 + bv.x; o0.y = acc01 + bv.y;
    float2 o1; o1.x = acc10 + bv.x; o1.y = acc11 + bv.y;
    *(float2*)(C + (size_t)(row0 + ty*2    )*N + col0 + tx*2) = o0;
    *(float2*)(C + (size_t)(row0 + ty*2 + 1)*N + col0 + tx*2) = o1;
}

// gemm_ih via 32x32 tiles: 512x1024 output per dir -> 16x32 tiles, 1024 blocks.
__global__ __launch_bounds__(256) void gemm_ih(const float* __restrict__ embeds,
                                               const float* __restrict__ Wf, const float* __restrict__ Wb,
                                               const float* __restrict__ biasf, const float* __restrict__ biasb,
                                               float* __restrict__ gxf, float* __restrict__ gxb) {
    int dir = blockIdx.z;
    gemm32_body(embeds, dir ? Wb : Wf, dir ? biasb : biasf, dir ? gxb : gxf,
                1024, 256, blockIdx.x, blockIdx.y);
}

// ---------------------------------------------------------------- LSTM recurrence (fp8 weights, 2-way K split)
// 512 threads: (j = tid&255, half = tid>>8). Halves the serial k-chain per
// step and doubles waves/SIMD to 2; half-1 dumps partials to LDS, half-0
// combines. Grid 256 = 2 replicas x 128 (replica 0 writes; keeps CUs busy).
__global__ __launch_bounds__(512) void lstm_rec(const float* __restrict__ gxf,
                                                const float* __restrict__ gxb,
                                                const uint4* __restrict__ qWf,
                                                const uint4* __restrict__ qWb,
                                                const float* __restrict__ scf,
                                                const float* __restrict__ scb,
                                                float* __restrict__ hall) {
    int blk  = blockIdx.x;        // 0..255: (rep, dir, pos)
    int rep  = blk >> 7;
    blk &= 127;
    int dir  = blk >> 6;
    int pos  = blk & 63;
    int tid  = threadIdx.x;
    int j    = tid & 255;         // cell
    int half = tid >> 8;          // K half
    const float* gx = dir ? gxb : gxf;
    const uint4* qW = dir ? qWb : qWf;
    float4 sc = ((const float4*)(dir ? scb : scf))[j];
    __shared__ __align__(16) float hs[256];
    __shared__ __align__(16) float part[256][4];
    if (tid < 256) hs[tid] = 0.0f;
    float cellc = 0.0f;
    __syncthreads();
    const uint4* qWh = qW + (half << 13);       // + half*32*256
    const float* hsh = hs + (half << 7);        // + half*32*4
    for (int s = 0; s < 8; ++s) {
        int t = dir ? (7 - s) : s;
        const float* g0 = gx + (size_t)(t*64 + pos)*1024;
        float ai = 0.0f, af = 0.0f, ag = 0.0f, ao = 0.0f;
        if (half == 0) { ai = g0[j]; af = g0[256+j]; ag = g0[512+j]; ao = g0[768+j]; }
        float qi = 0.0f, qf = 0.0f, qg = 0.0f, qo = 0.0f;
        #pragma unroll 8
        for (int k4 = 0; k4 < 32; ++k4) {
            uint4 wq = qWh[(k4 << 8) + j];
            float4 hp = *(const float4*)&hsh[k4*4];
            floatx2 pa, pb;
            pa = __builtin_amdgcn_cvt_pk_f32_fp8(wq.x, false);
            pb = __builtin_amdgcn_cvt_pk_f32_fp8(wq.x, true);
            qi = fmaf(pa.x, hp.x, qi); qf = fmaf(pa.y, hp.x, qf);
            qg = fmaf(pb.x, hp.x, qg); qo = fmaf(pb.y, hp.x, qo);
            pa = __builtin_amdgcn_cvt_pk_f32_fp8(wq.y, false);
            pb = __builtin_amdgcn_cvt_pk_f32_fp8(wq.y, true);
            qi = fmaf(pa.x, hp.y, qi); qf = fmaf(pa.y, hp.y, qf);
            qg = fmaf(pb.x, hp.y, qg); qo = fmaf(pb.y, hp.y, qo);
            pa = __builtin_amdgcn_cvt_pk_f32_fp8(wq.z, false);
            pb = __builtin_amdgcn_cvt_pk_f32_fp8(wq.z, true);
            qi = fmaf(pa.x, hp.z, qi); qf = fmaf(pa.y, hp.z, qf);
            qg = fmaf(pb.x, hp.z, qg); qo = fmaf(pb.y, hp.z, qo);
            pa = __builtin_amdgcn_cvt_pk_f32_fp8(wq.w, false);
            pb = __builtin_amdgcn_cvt_pk_f32_fp8(wq.w, true);
            qi = fmaf(pa.x, hp.w, qi); qf = fmaf(pa.y, hp.w, qf);
            qg = fmaf(pb.x, hp.w, qg); qo = fmaf(pb.y, hp.w, qo);
        }
        if (half) { part[j][0] = qi; part[j][1] = qf; part[j][2] = qg; part[j][3] = qo; }
        __syncthreads();
        if (half == 0) {
            float4 pr = *(const float4*)&part[j][0];
            ai = fmaf(sc.x, qi + pr.x, ai);
            af = fmaf(sc.y, qf + pr.y, af);
            ag = fmaf(sc.z, qg + pr.z, ag);
            ao = fmaf(sc.w, qo + pr.w, ao);
            cellc = sigf(af)*cellc + sigf(ai)*tanhf(ag);
            float h0 = sigf(ao)*tanhf(cellc);
            hs[j] = h0;
            if (rep == 0) hall[(size_t)(t*64 + pos)*512 + dir*256 + j] = h0;
        }
        __syncthreads();
    }
}

// ---------------------------------------------------------------- uv + p1 + p2 fused
__global__ __launch_bounds__(256) void post_lstm(const float* __restrict__ hall,
                                                 const float* __restrict__ Ws,
                                                 float* __restrict__ u, float* __restrict__ v,
                                                 const float* __restrict__ W1, const float* __restrict__ b1,
                                                 const float* __restrict__ W2, const float* __restrict__ b2,
                                                 float* __restrict__ p1, float* __restrict__ p2) {
    if (blockIdx.x < 512) {
        int bi = blockIdx.x;
        int i  = bi & 63;
        int tid = threadIdx.x;
        float pu = 0.0f, pv = 0.0f;
        for (int q = tid; q < 1536; q += 256) {
            int seg = q >> 9, kk = q & 511;
            float tv = 0.0f;
            if (seg == 0)       tv = hall[(size_t)bi*512 + kk];
            else if (seg == 1)  { if (i > 0)  tv = hall[(size_t)(bi-1)*512 + kk]; }
            else                { if (i < 63) tv = hall[(size_t)(bi+1)*512 + kk]; }
            pu = fmaf(tv, Ws[q],        pu);
            pv = fmaf(tv, Ws[1536 + q], pv);
        }
        for (int off = 32; off; off >>= 1) { pu += __shfl_xor(pu, off); pv += __shfl_xor(pv, off); }
        __shared__ float ru[4], rv[4];
        int wv = tid >> 6, lane = tid & 63;
        if (lane == 0) { ru[wv] = pu; rv[wv] = pv; }
        __syncthreads();
        if (tid == 0) { u[bi] = ru[0]+ru[1]+ru[2]+ru[3]; v[bi] = rv[0]+rv[1]+rv[2]+rv[3]; }
    } else {
        int gb = blockIdx.x - 512;         // 0..127
        int sel = gb >> 6; gb &= 63;       // 64 tiles per matrix: 16 row x 4 col
        gemm32_body(hall, sel ? W2 : W1, sel ? b2 : b1, sel ? p2 : p1,
                    128, 512, gb >> 2, gb & 3);
    }
}

// ---------------------------------------------------------------- Eisner + fused S-GEMM + finalize
// 512 threads/block; 256 blocks = 32 replicas x 8 batches (replica 0 commits).
// ROUND-7 BODY (best measured: 76.5 us). Round-8's register-mirror of row-i
// REGRESSED to 81.6 us despite halving LDS reads (conflicts 2.37M->1.24M):
// the DP is NOT LDS-throughput-bound -- added VALU (mirror cndmasks,
// all-lane epilogue) lengthened the critical path. Do not re-add.
// Phase A k4 loop: unroll 2 pragma is load-bearing -- full unroll spilled
// 174 MB of scratch (rounds 1-2). 1024-thr/16-lane variant regressed (round 5).
__global__ __launch_bounds__(512, 2) void eisner_final(const float* __restrict__ u,
                                                    const float* __restrict__ v,
                                                    const float* __restrict__ bs,
                                                    const float* __restrict__ p1,
                                                    const float* __restrict__ p2,
                                                    const float* __restrict__ prior,
                                                    const int* __restrict__ heads,
                                                    float* __restrict__ out) {
    int b   = blockIdx.x & 7;
    int rep = blockIdx.x >> 3;
    __shared__ __align__(16) float SMEM[3*64*TSTRIDE + 64];   // DP tables / stage / Sl (time-shared)
    __shared__ float su[64], sv[64], lseSb[64], sBest[1];
    float* T1 = &SMEM[0];
    float* T2 = &SMEM[64*TSTRIDE];
    float* T3 = &SMEM[2*64*TSTRIDE];
    int tid = threadIdx.x;
    float bsv = bs[0];
    if (tid < 64) {
        su[tid] = u[b*64 + tid];
        sv[tid] = v[b*64 + tid];
    }
    // ---- Phase A: S = p1[b] @ p2[b]^T (64x64x128), two K-halves through LDS
    const float4* g1 = (const float4*)(p1 + (size_t)b*8192);
    const float4* g2 = (const float4*)(p2 + (size_t)b*8192);
    float4* s1p = (float4*)SMEM;                   // 64 rows x 17 float4 (stride 68 floats)
    float4* s2p = (float4*)(SMEM + 64*TSTRIDE);
    int r   = tid >> 3;                            // output row / span index
    int sub = tid & 7;
    float acc[8];                                  // acc[q] = S[r][sub + 8q]
    #pragma unroll
    for (int q = 0; q < 8; ++q) acc[q] = 0.0f;
    for (int p = 0; p < 2; ++p) {
        #pragma unroll
        for (int f0 = 0; f0 < 4; ++f0) {
            int f = f0*512 + tid;
            int half = f >> 10;                    // 0: p1, 1: p2
            int ff = f & 1023;
            int row = ff >> 4, c4 = ff & 15;
            float4 vv = (half ? g2 : g1)[row*32 + (p<<4) + c4];
            (half ? s2p : s1p)[row*17 + c4] = vv;
        }
        __syncthreads();
        #pragma unroll 2
        for (int k4 = 0; k4 < 16; ++k4) {
            float4 a = s1p[r*17 + k4];
            #pragma unroll
            for (int q = 0; q < 8; ++q) {
                float4 bv = s2p[(sub + (q<<3))*17 + k4];
                acc[q] = fmaf(a.x, bv.x, acc[q]);
                acc[q] = fmaf(a.y, bv.y, acc[q]);
                acc[q] = fmaf(a.z, bv.z, acc[q]);
                acc[q] = fmaf(a.w, bv.w, acc[q]);
            }
        }
        __syncthreads();
    }
    // row-LSE of S straight from registers (8 lanes own a row)
    float pm = acc[0];
    #pragma unroll
    for (int q = 1; q < 8; ++q) pm = fmaxf(pm, acc[q]);
    pm = oct_max(pm);
    float ps = 0.0f;
    #pragma unroll
    for (int q = 0; q < 8; ++q) ps += exp2f((acc[q] - pm) * L2E);
    ps = oct_sum(ps);
    if (sub == 0) lseSb[r] = pm + log2f(ps) * LN2;
    // dump S into recycled stage LDS (stride 66)
    float* Sl = SMEM;
    #pragma unroll
    for (int q = 0; q < 8; ++q) Sl[r*66 + sub + (q<<3)] = acc[q];
    __syncthreads();
    // gold-arc score (wave 0 only), before the DP recycles Sl's LDS
    if (tid < 64) {
        int m = tid;
        float gv = -INFINITY;
        if (m >= 1) {
            int hd = heads[b*64 + m];
            gv = su[hd] + sv[m] + bsv + (Sl[hd*66 + m] - lseSb[hd])
               + prior[(size_t)(b*64 + hd)*64 + m] * (1.0f/64.0f);
        }
        float mm = gv;
        for (int off = 32; off; off >>= 1) mm = fmaxf(mm, __shfl_xor(mm, off));
        float se = (m >= 1) ? exp2f((gv - mm) * L2E) : 0.0f;
        for (int off = 32; off; off >>= 1) se += __shfl_xor(se, off);
        if (m == 0) sBest[0] = mm + log2f(se) * LN2;
    }
    __syncthreads();
    // ---- Phase B: DP table init
    if (tid < 64) {
        T1[tid*TSTRIDE + tid] = 0.0f;
        T2[tid*TSTRIDE + tid] = 0.0f;
        if (tid >= 1) T2[tid*TSTRIDE + tid-1] = 0.0f;
    }
    __syncthreads();
    int i = r;
    for (int w = 1; w < 64; ++w) {
        int ns = 64 - w;
        if (i < ns) {
            int j = i + w;
            const float* t1i = &T1[i*TSTRIDE];
            const float* t2i = &T2[i*TSTRIDE];
            const float* t3i = &T3[i*TSTRIDE];
            const float* t1j = &T1[j*TSTRIDE];
            const float* t2j = &T2[j*TSTRIDE];
            const float* t3j = &T3[j*TSTRIDE];
            float Dr = su[i] + sv[j] + bsv;
            float Dl = su[j] + sv[i] + bsv;
            float eDr = exp2f(Dr * L2E);           // loop-invariant, off the chain
            float eDl = exp2f(Dl * L2E);
            int k0 = i & ~3;
            float va[2][4], vr[2][4], vl[2][4];
            float M = -INFINITY;
            #pragma unroll
            for (int t = 0; t < 2; ++t) {
                int k = k0 + ((t << 3) + sub) * 4;
                if (k < j) {
                    float4 a1  = *(const float4*)&t1i[k];
                    float4 b1  = *(const float4*)&t2j[k];
                    float4 a2  = *(const float4*)&t3i[k];
                    float4 b2v = *(const float4*)&t1j[k];
                    float4 a3  = *(const float4*)&t2i[k];
                    float4 b3  = *(const float4*)&t3j[k];
                    #pragma unroll
                    for (int c = 0; c < 4; ++c) {
                        int kk = k + c;
                        bool in1 = (kk >= i   && kk < j);
                        bool in2 = (kk >= i+1 && kk < j);
                        float x1 = ((const float*)&a1)[c] + ((const float*)&b1)[c];
                        float x2 = ((const float*)&a2)[c] + ((const float*)&b2v)[c];
                        float x3 = ((const float*)&a3)[c] + ((const float*)&b3)[c];
                        va[t][c] = in1 ? x1 : -INFINITY;
                        vr[t][c] = in2 ? x2 : -INFINITY;
                        vl[t][c] = in2 ? x3 : -INFINITY;
                        M = fmaxf(M, va[t][c]);
                        M = fmaxf(M, vr[t][c]);
                        M = fmaxf(M, vl[t][c]);
                    }
                }
            }
            M = oct_max(M);
            float s1 = 0.0f, sr = 0.0f, sl = 0.0f;
            #pragma unroll
            for (int t = 0; t < 2; ++t) {
                int k = k0 + ((t << 3) + sub) * 4;
                if (k < j) {
                    #pragma unroll
                    for (int c = 0; c < 4; ++c) {
                        s1 += exp2f((va[t][c] - M) * L2E);
                        sr += exp2f((vr[t][c] - M) * L2E);
                        sl += exp2f((vl[t][c] - M) * L2E);
                    }
                }
            }
            s1 = oct_sum(s1);
            sr = oct_sum(sr);
            sl = oct_sum(sl);
            if (sub == 0) {
                float l2s1 = log2f(s1) * LN2;
                float Ir = M + l2s1 + Dr;
                float Il = M + l2s1 + Dl;
                float Cr = M + log2f(sr + s1 * eDr) * LN2;
                float Cl = M + log2f(sl + s1 * eDl) * LN2;
                T3[i*TSTRIDE + j] = Ir;
                T1[i*TSTRIDE + j] = Cr;
                T1[j*TSTRIDE + i] = Cr;
                T3[j*TSTRIDE + i] = Il;
                T2[i*TSTRIDE + j] = Cl;
                if (i >= 1) T2[j*TSTRIDE + i-1] = Cl;
            }
        }
        __syncthreads();
    }
    if (rep == 0 && tid == 0) {
        atomicAdd(out, -(sBest[0] - T1[0*TSTRIDE + 63]) * 0.125f);
    }
}

// ---------------------------------------------------------------- launch
extern "C" void kernel_launch(void* const* d_in, const int* in_sizes, int n_in,
                              void* d_out, int out_size, void* d_ws, size_t ws_size,
                              hipStream_t stream) {
    const int*   sents = (const int*)  d_in[0];
    const float* mask  = (const float*)d_in[1];
    const float* prior = (const float*)d_in[2];
    const int*   heads = (const int*)  d_in[3];
    const float* emb   = (const float*)d_in[4];
    const float* Wih_f = (const float*)d_in[5];
    const float* Whh_f = (const float*)d_in[6];
    const float* bih_f = (const float*)d_in[7];
    const float* bhh_f = (const float*)d_in[8];
    const float* Wih_b = (const float*)d_in[9];
    const float* Whh_b = (const float*)d_in[10];
    const float* bih_b = (const float*)d_in[11];
    const float* bhh_b = (const float*)d_in[12];
    const float* W1    = (const float*)d_in[13];
    const float* b1    = (const float*)d_in[14];
    const float* W2    = (const float*)d_in[15];
    const float* b2    = (const float*)d_in[16];
    const float* Ws    = (const float*)d_in[17];
    const float* bs    = (const float*)d_in[18];
    float* out = (float*)d_out;

    char* w = (char*)d_ws;
    float* embeds = (float*)(w + 0);                 // 512 KB
    float* gxf    = (float*)(w + 524288);            // 2 MB
    float* gxb    = (float*)(w + 2621440);           // 2 MB
    uint4* qWf    = (uint4*)(w + 4718592);           // 256 KB
    uint4* qWb    = (uint4*)(w + 4980736);           // 256 KB
    float* scf    = (float*)(w + 5242880);           // 4 KB
    float* scb    = (float*)(w + 5246976);           // 4 KB
    float* biasf  = (float*)(w + 5767168);           // 4 KB
    float* biasb  = (float*)(w + 5771264);           // 4 KB
    float* hall   = (float*)(w + 5775360);           // 1 MB
    float* uArr   = (float*)(w + 6823936);
    float* vArr   = (float*)(w + 6825984);
    float* p1     = (float*)(w + 6828032);
    float* p2     = (float*)(w + 7090176);

    prep_all<<<640, 256, 0, stream>>>(Whh_f, Whh_b, bih_f, bhh_f, bih_b, bhh_b,
                                      qWf, qWb, scf, scb, biasf, biasb,
                                      sents, mask, emb, embeds, out);
    gemm_ih<<<dim3(16,32,2), 256, 0, stream>>>(embeds, Wih_f, Wih_b, biasf, biasb, gxf, gxb);
    lstm_rec<<<256, 512, 0, stream>>>(gxf, gxb, qWf, qWb, scf, scb, hall);
    post_lstm<<<640, 256, 0, stream>>>(hall, Ws, uArr, vArr, W1, b1, W2, b2, p1, p2);
    eisner_final<<<256, 512, 0, stream>>>(uArr, vArr, bs, p1, p2, prior, heads, out);
    (void)in_sizes; (void)n_in; (void)out_size; (void)ws_size;
}

// Round 12
// 250.204 us; speedup vs baseline: 1.0132x; 1.0132x over previous
//
#include <hip/hip_runtime.h>
#include <hip/hip_bf16.h>
#include <math.h>

#define L2E 1.44269504f
#define LN2 0.69314718f
#define TSTRIDE 68

typedef __attribute__((ext_vector_type(2))) float floatx2;

__device__ __forceinline__ float sigf(float x){ return 1.0f/(1.0f+expf(-x)); }

__device__ __forceinline__ float quad_max(float x) {
    x = fmaxf(x, __int_as_float(__builtin_amdgcn_mov_dpp(__float_as_int(x), 0xB1, 0xF, 0xF, true)));
    x = fmaxf(x, __int_as_float(__builtin_amdgcn_mov_dpp(__float_as_int(x), 0x4E, 0xF, 0xF, true)));
    return x;
}
// 8-lane (aligned consecutive group) reductions -- PURE DPP, no LDS:
// xor1 = quad_perm swap-adjacent (0xB1), xor2 = quad_perm swap-pairs (0x4E),
// quad<->quad exchange within the 8-lane half-row = row_half_mirror (0x141).
__device__ __forceinline__ float oct_max(float x) {
    x = fmaxf(x, __int_as_float(__builtin_amdgcn_mov_dpp(__float_as_int(x), 0xB1, 0xF, 0xF, true)));
    x = fmaxf(x, __int_as_float(__builtin_amdgcn_mov_dpp(__float_as_int(x), 0x4E, 0xF, 0xF, true)));
    x = fmaxf(x, __int_as_float(__builtin_amdgcn_mov_dpp(__float_as_int(x), 0x141, 0xF, 0xF, true)));
    return x;
}
__device__ __forceinline__ float oct_sum(float x) {
    x += __int_as_float(__builtin_amdgcn_mov_dpp(__float_as_int(x), 0xB1, 0xF, 0xF, true));
    x += __int_as_float(__builtin_amdgcn_mov_dpp(__float_as_int(x), 0x4E, 0xF, 0xF, true));
    x += __int_as_float(__builtin_amdgcn_mov_dpp(__float_as_int(x), 0x141, 0xF, 0xF, true));
    return x;
}

// ---------------------------------------------------------------- prep: embed + bias + coalesced fp8 pack
__global__ __launch_bounds__(256) void prep_all(const float* __restrict__ Whh_f, const float* __restrict__ Whh_b,
                             const float* __restrict__ bih_f, const float* __restrict__ bhh_f,
                             const float* __restrict__ bih_b, const float* __restrict__ bhh_b,
                             uint4* __restrict__ qWf, uint4* __restrict__ qWb,
                             float* __restrict__ scf, float* __restrict__ scb,
                             float* __restrict__ biasf, float* __restrict__ biasb,
                             const int* __restrict__ sents, const float* __restrict__ mask,
                             const float* __restrict__ emb, float* __restrict__ embeds,
                             float* __restrict__ out) {
    int tid = threadIdx.x;
    if (blockIdx.x < 512) {
        int bl = blockIdx.x;
        const int*   srow = sents + bl*32;
        const float* mrow = mask  + bl*32;
        float acc = 0.0f, el = 0.0f;
        for (int w = 0; w < 32; ++w) {
            float m = mrow[w];
            el  += m;
            acc += emb[(size_t)srow[w]*256 + tid] * m;
        }
        float den = el + (el == 0.0f ? 1.0f : 0.0f);
        embeds[bl*256 + tid] = acc / den;
        if (bl == 0)      { for (int q = tid; q < 1024; q += 256) biasf[q] = bih_f[q] + bhh_f[q]; }
        else if (bl == 1) { for (int q = tid; q < 1024; q += 256) biasb[q] = bih_b[q] + bhh_b[q]; }
        else if (bl == 2 && tid == 0) out[0] = 0.0f;
    } else {
        int pb  = blockIdx.x - 512;      // 0..127
        int dir = pb >> 6;
        int cg  = pb & 63;               // cell group of 4
        const float* W = dir ? Whh_b : Whh_f;
        uint4* qW = dir ? qWb : qWf;
        float* sc = dir ? scb : scf;
        __shared__ float Wl[16][260];    // 16 rows (4 gates x 4 cells), padded
        __shared__ float sL[16];         // row scales [g*4+jj]
        #pragma unroll
        for (int lr = 0; lr < 16; ++lr) {
            int g = lr >> 2, jj = lr & 3;
            int rowid = g*256 + cg*4 + jj;
            Wl[lr][tid] = W[(size_t)rowid*256 + tid];
        }
        __syncthreads();
        if (tid < 64) {
            int lr = tid >> 2, sub = tid & 3;
            float mx = 0.0f;
            for (int m = 0; m < 64; ++m) mx = fmaxf(mx, fabsf(Wl[lr][sub*64 + m]));
            mx = quad_max(mx);
            if (sub == 0) sL[lr] = mx * (1.0f/240.0f) + 1e-30f;
        }
        __syncthreads();
        int k4 = tid >> 2, jj = tid & 3;
        float is0 = 1.0f / sL[0*4 + jj];
        float is1 = 1.0f / sL[1*4 + jj];
        float is2 = 1.0f / sL[2*4 + jj];
        float is3 = 1.0f / sL[3*4 + jj];
        uint4 q;
        unsigned int* qq = (unsigned int*)&q;
        #pragma unroll
        for (int kk = 0; kk < 4; ++kk) {
            int k = k4*4 + kk;
            int d = 0;
            d = __builtin_amdgcn_cvt_pk_fp8_f32(Wl[0*4+jj][k]*is0, Wl[1*4+jj][k]*is1, d, false);
            d = __builtin_amdgcn_cvt_pk_fp8_f32(Wl[2*4+jj][k]*is2, Wl[3*4+jj][k]*is3, d, true);
            qq[kk] = (unsigned int)d;
        }
        qW[k4*256 + cg*4 + jj] = q;
        if (tid < 16) {
            int g = tid >> 2, j2 = tid & 3;
            sc[(cg*4 + j2)*4 + g] = sL[g*4 + j2];
        }
    }
}

// ---------------------------------------------------------------- 64x64 GEMM body, 4x4 micro-tile
// Keep for gemm_ih: round-11 measured the 32-tile variant REGRESSING ~7 us
// there (worse LDS-read:FMA ratio, 2x operand traffic; gemm_ih's 256 blocks
// already cover all CUs -- "more blocks" only pays when blocks < CUs).
__device__ __forceinline__ void gemm64_body(const float* __restrict__ A,
                                            const float* __restrict__ Bm,
                                            const float* __restrict__ bias,
                                            float* __restrict__ C,
                                            int N, int K, int bx, int by) {
    __shared__ __align__(16) float As[32][68];
    __shared__ __align__(16) float Bs[32][68];
    int tid = threadIdx.x;
    int tx = tid & 15, ty = tid >> 4;
    int row0 = bx * 64, col0 = by * 64;
    float acc[4][4];
    #pragma unroll
    for (int r = 0; r < 4; ++r)
        #pragma unroll
        for (int c = 0; c < 4; ++c) acc[r][c] = 0.0f;
    int lr = tid >> 2;
    int lc = (tid & 3) * 8;
    for (int k0 = 0; k0 < K; k0 += 32) {
        float4 a0 = *(const float4*)(A  + (size_t)(row0+lr)*K + k0 + lc);
        float4 a1 = *(const float4*)(A  + (size_t)(row0+lr)*K + k0 + lc + 4);
        float4 b0 = *(const float4*)(Bm + (size_t)(col0+lr)*K + k0 + lc);
        float4 b1 = *(const float4*)(Bm + (size_t)(col0+lr)*K + k0 + lc + 4);
        As[lc  ][lr] = a0.x; As[lc+1][lr] = a0.y; As[lc+2][lr] = a0.z; As[lc+3][lr] = a0.w;
        As[lc+4][lr] = a1.x; As[lc+5][lr] = a1.y; As[lc+6][lr] = a1.z; As[lc+7][lr] = a1.w;
        Bs[lc  ][lr] = b0.x; Bs[lc+1][lr] = b0.y; Bs[lc+2][lr] = b0.z; Bs[lc+3][lr] = b0.w;
        Bs[lc+4][lr] = b1.x; Bs[lc+5][lr] = b1.y; Bs[lc+6][lr] = b1.z; Bs[lc+7][lr] = b1.w;
        __syncthreads();
        #pragma unroll
        for (int kc = 0; kc < 32; ++kc) {
            float4 xa = *(const float4*)&As[kc][ty*4];
            float4 xb = *(const float4*)&Bs[kc][tx*4];
            acc[0][0] = fmaf(xa.x, xb.x, acc[0][0]);
            acc[0][1] = fmaf(xa.x, xb.y, acc[0][1]);
            acc[0][2] = fmaf(xa.x, xb.z, acc[0][2]);
            acc[0][3] = fmaf(xa.x, xb.w, acc[0][3]);
            acc[1][0] = fmaf(xa.y, xb.x, acc[1][0]);
            acc[1][1] = fmaf(xa.y, xb.y, acc[1][1]);
            acc[1][2] = fmaf(xa.y, xb.z, acc[1][2]);
            acc[1][3] = fmaf(xa.y, xb.w, acc[1][3]);
            acc[2][0] = fmaf(xa.z, xb.x, acc[2][0]);
            acc[2][1] = fmaf(xa.z, xb.y, acc[2][1]);
            acc[2][2] = fmaf(xa.z, xb.z, acc[2][2]);
            acc[2][3] = fmaf(xa.z, xb.w, acc[2][3]);
            acc[3][0] = fmaf(xa.w, xb.x, acc[3][0]);
            acc[3][1] = fmaf(xa.w, xb.y, acc[3][1]);
            acc[3][2] = fmaf(xa.w, xb.z, acc[3][2]);
            acc[3][3] = fmaf(xa.w, xb.w, acc[3][3]);
        }
        __syncthreads();
    }
    float4 bv = bias ? *(const float4*)&bias[col0 + tx*4] : make_float4(0.f,0.f,0.f,0.f);
    #pragma unroll
    for (int r = 0; r < 4; ++r) {
        float4 o;
        o.x = acc[r][0] + bv.x; o.y = acc[r][1] + bv.y;
        o.z = acc[r][2] + bv.z; o.w = acc[r][3] + bv.w;
        *(float4*)(C + (size_t)(row0 + ty*4 + r)*N + col0 + tx*4) = o;
    }
}

// ---------------------------------------------------------------- 32x32 GEMM body, 2x2 micro-tile
// For the p1/p2 projection ONLY (32 output tiles < 256 CUs there, so the
// extra block count buys real parallelism).
__device__ __forceinline__ void gemm32_body(const float* __restrict__ A,
                                            const float* __restrict__ Bm,
                                            const float* __restrict__ bias,
                                            float* __restrict__ C,
                                            int N, int K, int bx, int by) {
    __shared__ __align__(16) float As[32][36];
    __shared__ __align__(16) float Bs[32][36];
    int tid = threadIdx.x;
    int tx = tid & 15, ty = tid >> 4;
    int row0 = bx * 32, col0 = by * 32;
    float acc00 = 0.f, acc01 = 0.f, acc10 = 0.f, acc11 = 0.f;
    int lr = tid >> 3;            // 0..31
    int lc = (tid & 7) * 4;       // 0..28
    for (int k0 = 0; k0 < K; k0 += 32) {
        float4 a0 = *(const float4*)(A  + (size_t)(row0+lr)*K + k0 + lc);
        float4 b0 = *(const float4*)(Bm + (size_t)(col0+lr)*K + k0 + lc);
        As[lc  ][lr] = a0.x; As[lc+1][lr] = a0.y; As[lc+2][lr] = a0.z; As[lc+3][lr] = a0.w;
        Bs[lc  ][lr] = b0.x; Bs[lc+1][lr] = b0.y; Bs[lc+2][lr] = b0.z; Bs[lc+3][lr] = b0.w;
        __syncthreads();
        #pragma unroll
        for (int kc = 0; kc < 32; ++kc) {
            float2 xa = *(const float2*)&As[kc][ty*2];
            float2 xb = *(const float2*)&Bs[kc][tx*2];
            acc00 = fmaf(xa.x, xb.x, acc00);
            acc01 = fmaf(xa.x, xb.y, acc01);
            acc10 = fmaf(xa.y, xb.x, acc10);
            acc11 = fmaf(xa.y, xb.y, acc11);
        }
        __syncthreads();
    }
    float2 bv = *(const float2*)&bias[col0 + tx*2];
    float2 o0; o0.x = acc00 + bv.x; o0.y = acc01 + bv.y;
    float2 o1; o1.x = acc10 + bv.x; o1.y = acc11 + bv.y;
    *(float2*)(C + (size_t)(row0 + ty*2    )*N + col0 + tx*2) = o0;
    *(float2*)(C + (size_t)(row0 + ty*2 + 1)*N + col0 + tx*2) = o1;
}

__global__ __launch_bounds__(256) void gemm_ih(const float* __restrict__ embeds,
                                               const float* __restrict__ Wf, const float* __restrict__ Wb,
                                               const float* __restrict__ biasf, const float* __restrict__ biasb,
                                               float* __restrict__ gxf, float* __restrict__ gxb) {
    int dir = blockIdx.z;
    gemm64_body(embeds, dir ? Wb : Wf, dir ? biasb : biasf, dir ? gxb : gxf,
                1024, 256, blockIdx.x, blockIdx.y);
}

// ---------------------------------------------------------------- LSTM recurrence (fp8 weights, 2-way K split)
__global__ __launch_bounds__(512) void lstm_rec(const float* __restrict__ gxf,
                                                const float* __restrict__ gxb,
                                                const uint4* __restrict__ qWf,
                                                const uint4* __restrict__ qWb,
                                                const float* __restrict__ scf,
                                                const float* __restrict__ scb,
                                                float* __restrict__ hall) {
    int blk  = blockIdx.x;        // 0..255: (rep, dir, pos)
    int rep  = blk >> 7;
    blk &= 127;
    int dir  = blk >> 6;
    int pos  = blk & 63;
    int tid  = threadIdx.x;
    int j    = tid & 255;         // cell
    int half = tid >> 8;          // K half
    const float* gx = dir ? gxb : gxf;
    const uint4* qW = dir ? qWb : qWf;
    float4 sc = ((const float4*)(dir ? scb : scf))[j];
    __shared__ __align__(16) float hs[256];
    __shared__ __align__(16) float part[256][4];
    if (tid < 256) hs[tid] = 0.0f;
    float cellc = 0.0f;
    __syncthreads();
    const uint4* qWh = qW + (half << 13);       // + half*32*256
    const float* hsh = hs + (half << 7);        // + half*32*4
    for (int s = 0; s < 8; ++s) {
        int t = dir ? (7 - s) : s;
        const float* g0 = gx + (size_t)(t*64 + pos)*1024;
        float ai = 0.0f, af = 0.0f, ag = 0.0f, ao = 0.0f;
        if (half == 0) { ai = g0[j]; af = g0[256+j]; ag = g0[512+j]; ao = g0[768+j]; }
        float qi = 0.0f, qf = 0.0f, qg = 0.0f, qo = 0.0f;
        #pragma unroll 8
        for (int k4 = 0; k4 < 32; ++k4) {
            uint4 wq = qWh[(k4 << 8) + j];
            float4 hp = *(const float4*)&hsh[k4*4];
            floatx2 pa, pb;
            pa = __builtin_amdgcn_cvt_pk_f32_fp8(wq.x, false);
            pb = __builtin_amdgcn_cvt_pk_f32_fp8(wq.x, true);
            qi = fmaf(pa.x, hp.x, qi); qf = fmaf(pa.y, hp.x, qf);
            qg = fmaf(pb.x, hp.x, qg); qo = fmaf(pb.y, hp.x, qo);
            pa = __builtin_amdgcn_cvt_pk_f32_fp8(wq.y, false);
            pb = __builtin_amdgcn_cvt_pk_f32_fp8(wq.y, true);
            qi = fmaf(pa.x, hp.y, qi); qf = fmaf(pa.y, hp.y, qf);
            qg = fmaf(pb.x, hp.y, qg); qo = fmaf(pb.y, hp.y, qo);
            pa = __builtin_amdgcn_cvt_pk_f32_fp8(wq.z, false);
            pb = __builtin_amdgcn_cvt_pk_f32_fp8(wq.z, true);
            qi = fmaf(pa.x, hp.z, qi); qf = fmaf(pa.y, hp.z, qf);
            qg = fmaf(pb.x, hp.z, qg); qo = fmaf(pb.y, hp.z, qo);
            pa = __builtin_amdgcn_cvt_pk_f32_fp8(wq.w, false);
            pb = __builtin_amdgcn_cvt_pk_f32_fp8(wq.w, true);
            qi = fmaf(pa.x, hp.w, qi); qf = fmaf(pa.y, hp.w, qf);
            qg = fmaf(pb.x, hp.w, qg); qo = fmaf(pb.y, hp.w, qo);
        }
        if (half) { part[j][0] = qi; part[j][1] = qf; part[j][2] = qg; part[j][3] = qo; }
        __syncthreads();
        if (half == 0) {
            float4 pr = *(const float4*)&part[j][0];
            ai = fmaf(sc.x, qi + pr.x, ai);
            af = fmaf(sc.y, qf + pr.y, af);
            ag = fmaf(sc.z, qg + pr.z, ag);
            ao = fmaf(sc.w, qo + pr.w, ao);
            cellc = sigf(af)*cellc + sigf(ai)*tanhf(ag);
            float h0 = sigf(ao)*tanhf(cellc);
            hs[j] = h0;
            if (rep == 0) hall[(size_t)(t*64 + pos)*512 + dir*256 + j] = h0;
        }
        __syncthreads();
    }
}

// ---------------------------------------------------------------- uv + p1 + p2 fused
__global__ __launch_bounds__(256) void post_lstm(const float* __restrict__ hall,
                                                 const float* __restrict__ Ws,
                                                 float* __restrict__ u, float* __restrict__ v,
                                                 const float* __restrict__ W1, const float* __restrict__ b1,
                                                 const float* __restrict__ W2, const float* __restrict__ b2,
                                                 float* __restrict__ p1, float* __restrict__ p2) {
    if (blockIdx.x < 512) {
        int bi = blockIdx.x;
        int i  = bi & 63;
        int tid = threadIdx.x;
        float pu = 0.0f, pv = 0.0f;
        for (int q = tid; q < 1536; q += 256) {
            int seg = q >> 9, kk = q & 511;
            float tv = 0.0f;
            if (seg == 0)       tv = hall[(size_t)bi*512 + kk];
            else if (seg == 1)  { if (i > 0)  tv = hall[(size_t)(bi-1)*512 + kk]; }
            else                { if (i < 63) tv = hall[(size_t)(bi+1)*512 + kk]; }
            pu = fmaf(tv, Ws[q],        pu);
            pv = fmaf(tv, Ws[1536 + q], pv);
        }
        for (int off = 32; off; off >>= 1) { pu += __shfl_xor(pu, off); pv += __shfl_xor(pv, off); }
        __shared__ float ru[4], rv[4];
        int wv = tid >> 6, lane = tid & 63;
        if (lane == 0) { ru[wv] = pu; rv[wv] = pv; }
        __syncthreads();
        if (tid == 0) { u[bi] = ru[0]+ru[1]+ru[2]+ru[3]; v[bi] = rv[0]+rv[1]+rv[2]+rv[3]; }
    } else {
        int gb = blockIdx.x - 512;         // 0..127
        int sel = gb >> 6; gb &= 63;       // 64 tiles per matrix: 16 row x 4 col
        gemm32_body(hall, sel ? W2 : W1, sel ? b2 : b1, sel ? p2 : p1,
                    128, 512, gb >> 2, gb & 3);
    }
}

// ---------------------------------------------------------------- Eisner + fused S-GEMM + finalize
// 512 threads/block; 256 blocks = 32 replicas x 8 batches (replica 0 commits).
// ROUND-7 BODY (best measured: 76.5 us) + loop-invariant su/sv hoist (the
// __syncthreads each level forces shared re-reads; su/sv never change after
// init, so registers are legal and save 2 ds_reads + adds per level).
// Round-8's register-mirror REGRESSED (not LDS-throughput-bound); round-5's
// 1024-thr/16-lane REGRESSED (issue growth). Do not re-add either.
// Phase A k4 loop: unroll 2 pragma is load-bearing -- full unroll spilled
// 174 MB of scratch (rounds 1-2).
__global__ __launch_bounds__(512, 2) void eisner_final(const float* __restrict__ u,
                                                    const float* __restrict__ v,
                                                    const float* __restrict__ bs,
                                                    const float* __restrict__ p1,
                                                    const float* __restrict__ p2,
                                                    const float* __restrict__ prior,
                                                    const int* __restrict__ heads,
                                                    float* __restrict__ out) {
    int b   = blockIdx.x & 7;
    int rep = blockIdx.x >> 3;
    __shared__ __align__(16) float SMEM[3*64*TSTRIDE + 64];   // DP tables / stage / Sl (time-shared)
    __shared__ float su[64], sv[64], lseSb[64], sBest[1];
    float* T1 = &SMEM[0];
    float* T2 = &SMEM[64*TSTRIDE];
    float* T3 = &SMEM[2*64*TSTRIDE];
    int tid = threadIdx.x;
    float bsv = bs[0];
    if (tid < 64) {
        su[tid] = u[b*64 + tid];
        sv[tid] = v[b*64 + tid];
    }
    // ---- Phase A: S = p1[b] @ p2[b]^T (64x64x128), two K-halves through LDS
    const float4* g1 = (const float4*)(p1 + (size_t)b*8192);
    const float4* g2 = (const float4*)(p2 + (size_t)b*8192);
    float4* s1p = (float4*)SMEM;                   // 64 rows x 17 float4 (stride 68 floats)
    float4* s2p = (float4*)(SMEM + 64*TSTRIDE);
    int r   = tid >> 3;                            // output row / span index
    int sub = tid & 7;
    float acc[8];                                  // acc[q] = S[r][sub + 8q]
    #pragma unroll
    for (int q = 0; q < 8; ++q) acc[q] = 0.0f;
    for (int p = 0; p < 2; ++p) {
        #pragma unroll
        for (int f0 = 0; f0 < 4; ++f0) {
            int f = f0*512 + tid;
            int half = f >> 10;                    // 0: p1, 1: p2
            int ff = f & 1023;
            int row = ff >> 4, c4 = ff & 15;
            float4 vv = (half ? g2 : g1)[row*32 + (p<<4) + c4];
            (half ? s2p : s1p)[row*17 + c4] = vv;
        }
        __syncthreads();
        #pragma unroll 2
        for (int k4 = 0; k4 < 16; ++k4) {
            float4 a = s1p[r*17 + k4];
            #pragma unroll
            for (int q = 0; q < 8; ++q) {
                float4 bv = s2p[(sub + (q<<3))*17 + k4];
                acc[q] = fmaf(a.x, bv.x, acc[q]);
                acc[q] = fmaf(a.y, bv.y, acc[q]);
                acc[q] = fmaf(a.z, bv.z, acc[q]);
                acc[q] = fmaf(a.w, bv.w, acc[q]);
            }
        }
        __syncthreads();
    }
    // row-LSE of S straight from registers (8 lanes own a row)
    float pm = acc[0];
    #pragma unroll
    for (int q = 1; q < 8; ++q) pm = fmaxf(pm, acc[q]);
    pm = oct_max(pm);
    float ps = 0.0f;
    #pragma unroll
    for (int q = 0; q < 8; ++q) ps += exp2f((acc[q] - pm) * L2E);
    ps = oct_sum(ps);
    if (sub == 0) lseSb[r] = pm + log2f(ps) * LN2;
    // dump S into recycled stage LDS (stride 66)
    float* Sl = SMEM;
    #pragma unroll
    for (int q = 0; q < 8; ++q) Sl[r*66 + sub + (q<<3)] = acc[q];
    __syncthreads();
    // gold-arc score (wave 0 only), before the DP recycles Sl's LDS
    if (tid < 64) {
        int m = tid;
        float gv = -INFINITY;
        if (m >= 1) {
            int hd = heads[b*64 + m];
            gv = su[hd] + sv[m] + bsv + (Sl[hd*66 + m] - lseSb[hd])
               + prior[(size_t)(b*64 + hd)*64 + m] * (1.0f/64.0f);
        }
        float mm = gv;
        for (int off = 32; off; off >>= 1) mm = fmaxf(mm, __shfl_xor(mm, off));
        float se = (m >= 1) ? exp2f((gv - mm) * L2E) : 0.0f;
        for (int off = 32; off; off >>= 1) se += __shfl_xor(se, off);
        if (m == 0) sBest[0] = mm + log2f(se) * LN2;
    }
    __syncthreads();
    // ---- Phase B: DP table init
    if (tid < 64) {
        T1[tid*TSTRIDE + tid] = 0.0f;
        T2[tid*TSTRIDE + tid] = 0.0f;
        if (tid >= 1) T2[tid*TSTRIDE + tid-1] = 0.0f;
    }
    __syncthreads();
    int i = r;
    float sui_b = su[i] + bsv;     // loop-invariant (su/sv never rewritten)
    float svi_b = sv[i] + bsv;
    for (int w = 1; w < 64; ++w) {
        int ns = 64 - w;
        if (i < ns) {
            int j = i + w;
            const float* t1i = &T1[i*TSTRIDE];
            const float* t2i = &T2[i*TSTRIDE];
            const float* t3i = &T3[i*TSTRIDE];
            const float* t1j = &T1[j*TSTRIDE];
            const float* t2j = &T2[j*TSTRIDE];
            const float* t3j = &T3[j*TSTRIDE];
            float Dr = sui_b + sv[j];
            float Dl = su[j] + svi_b;
            float eDr = exp2f(Dr * L2E);           // loop-invariant per level, off the chain
            float eDl = exp2f(Dl * L2E);
            int k0 = i & ~3;
            float va[2][4], vr[2][4], vl[2][4];
            float M = -INFINITY;
            #pragma unroll
            for (int t = 0; t < 2; ++t) {
                int k = k0 + ((t << 3) + sub) * 4;
                if (k < j) {
                    float4 a1  = *(const float4*)&t1i[k];
                    float4 b1  = *(const float4*)&t2j[k];
                    float4 a2  = *(const float4*)&t3i[k];
                    float4 b2v = *(const float4*)&t1j[k];
                    float4 a3  = *(const float4*)&t2i[k];
                    float4 b3  = *(const float4*)&t3j[k];
                    #pragma unroll
                    for (int c = 0; c < 4; ++c) {
                        int kk = k + c;
                        bool in1 = (kk >= i   && kk < j);
                        bool in2 = (kk >= i+1 && kk < j);
                        float x1 = ((const float*)&a1)[c] + ((const float*)&b1)[c];
                        float x2 = ((const float*)&a2)[c] + ((const float*)&b2v)[c];
                        float x3 = ((const float*)&a3)[c] + ((const float*)&b3)[c];
                        va[t][c] = in1 ? x1 : -INFINITY;
                        vr[t][c] = in2 ? x2 : -INFINITY;
                        vl[t][c] = in2 ? x3 : -INFINITY;
                        M = fmaxf(M, va[t][c]);
                        M = fmaxf(M, vr[t][c]);
                        M = fmaxf(M, vl[t][c]);
                    }
                }
            }
            M = oct_max(M);
            float s1 = 0.0f, sr = 0.0f, sl = 0.0f;
            #pragma unroll
            for (int t = 0; t < 2; ++t) {
                int k = k0 + ((t << 3) + sub) * 4;
                if (k < j) {
                    #pragma unroll
                    for (int c = 0; c < 4; ++c) {
                        s1 += exp2f((va[t][c] - M) * L2E);
                        sr += exp2f((vr[t][c] - M) * L2E);
                        sl += exp2f((vl[t][c] - M) * L2E);
                    }
                }
            }
            s1 = oct_sum(s1);
            sr = oct_sum(sr);
            sl = oct_sum(sl);
            if (sub == 0) {
                float l2s1 = log2f(s1) * LN2;
                float Ir = M + l2s1 + Dr;
                float Il = M + l2s1 + Dl;
                float Cr = M + log2f(sr + s1 * eDr) * LN2;
                float Cl = M + log2f(sl + s1 * eDl) * LN2;
                T3[i*TSTRIDE + j] = Ir;
                T1[i*TSTRIDE + j] = Cr;
                T1[j*TSTRIDE + i] = Cr;
                T3[j*TSTRIDE + i] = Il;
                T2[i*TSTRIDE + j] = Cl;
                if (i >= 1) T2[j*TSTRIDE + i-1] = Cl;
            }
        }
        __syncthreads();
    }
    if (rep == 0 && tid == 0) {
        atomicAdd(out, -(sBest[0] - T1[0*TSTRIDE + 63]) * 0.125f);
    }
}

// ---------------------------------------------------------------- launch
extern "C" void kernel_launch(void* const* d_in, const int* in_sizes, int n_in,
                              void* d_out, int out_size, void* d_ws, size_t ws_size,
                              hipStream_t stream) {
    const int*   sents = (const int*)  d_in[0];
    const float* mask  = (const float*)d_in[1];
    const float* prior = (const float*)d_in[2];
    const int*   heads = (const int*)  d_in[3];
    const float* emb   = (const float*)d_in[4];
    const float* Wih_f = (const float*)d_in[5];
    const float* Whh_f = (const float*)d_in[6];
    const float* bih_f = (const float*)d_in[7];
    const float* bhh_f = (const float*)d_in[8];
    const float* Wih_b = (const float*)d_in[9];
    const float* Whh_b = (const float*)d_in[10];
    const float* bih_b = (const float*)d_in[11];
    const float* bhh_b = (const float*)d_in[12];
    const float* W1    = (const float*)d_in[13];
    const float* b1    = (const float*)d_in[14];
    const float* W2    = (const float*)d_in[15];
    const float* b2    = (const float*)d_in[16];
    const float* Ws    = (const float*)d_in[17];
    const float* bs    = (const float*)d_in[18];
    float* out = (float*)d_out;

    char* w = (char*)d_ws;
    float* embeds = (float*)(w + 0);                 // 512 KB
    float* gxf    = (float*)(w + 524288);            // 2 MB
    float* gxb    = (float*)(w + 2621440);           // 2 MB
    uint4* qWf    = (uint4*)(w + 4718592);           // 256 KB
    uint4* qWb    = (uint4*)(w + 4980736);           // 256 KB
    float* scf    = (float*)(w + 5242880);           // 4 KB
    float* scb    = (float*)(w + 5246976);           // 4 KB
    float* biasf  = (float*)(w + 5767168);           // 4 KB
    float* biasb  = (float*)(w + 5771264);           // 4 KB
    float* hall   = (float*)(w + 5775360);           // 1 MB
    float* uArr   = (float*)(w + 6823936);
    float* vArr   = (float*)(w + 6825984);
    float* p1     = (float*)(w + 6828032);
    float* p2     = (float*)(w + 7090176);

    prep_all<<<640, 256, 0, stream>>>(Whh_f, Whh_b, bih_f, bhh_f, bih_b, bhh_b,
                                      qWf, qWb, scf, scb, biasf, biasb,
                                      sents, mask, emb, embeds, out);
    gemm_ih<<<dim3(8,16,2), 256, 0, stream>>>(embeds, Wih_f, Wih_b, biasf, biasb, gxf, gxb);
    lstm_rec<<<256, 512, 0, stream>>>(gxf, gxb, qWf, qWb, scf, scb, hall);
    post_lstm<<<640, 256, 0, stream>>>(hall, Ws, uArr, vArr, W1, b1, W2, b2, p1, p2);
    eisner_final<<<256, 512, 0, stream>>>(uArr, vArr, bs, p1, p2, prior, heads, out);
    (void)in_sizes; (void)n_in; (void)out_size; (void)ws_size;
}

// Round 13
// 208.893 us; speedup vs baseline: 1.2135x; 1.1978x over previous
//
#include <hip/hip_runtime.h>
#include <hip/hip_bf16.h>
#include <math.h>

#define L2E 1.44269504f
#define LN2 0.69314718f
#define TSTRIDE 68

typedef __attribute__((ext_vector_type(2))) float floatx2;

__device__ __forceinline__ float sigf(float x){ return 1.0f/(1.0f+expf(-x)); }

__device__ __forceinline__ float quad_max(float x) {
    x = fmaxf(x, __int_as_float(__builtin_amdgcn_mov_dpp(__float_as_int(x), 0xB1, 0xF, 0xF, true)));
    x = fmaxf(x, __int_as_float(__builtin_amdgcn_mov_dpp(__float_as_int(x), 0x4E, 0xF, 0xF, true)));
    return x;
}
// 8-lane (aligned consecutive group) sum -- PURE DPP, no LDS:
// xor1 = quad_perm swap-adjacent (0xB1), xor2 = quad_perm swap-pairs (0x4E),
// quad<->quad exchange within the 8-lane half-row = row_half_mirror (0x141).
__device__ __forceinline__ float oct_sum(float x) {
    x += __int_as_float(__builtin_amdgcn_mov_dpp(__float_as_int(x), 0xB1, 0xF, 0xF, true));
    x += __int_as_float(__builtin_amdgcn_mov_dpp(__float_as_int(x), 0x4E, 0xF, 0xF, true));
    x += __int_as_float(__builtin_amdgcn_mov_dpp(__float_as_int(x), 0x141, 0xF, 0xF, true));
    return x;
}

// ---------------------------------------------------------------- prep: embed + bias + coalesced fp8 pack
__global__ __launch_bounds__(256) void prep_all(const float* __restrict__ Whh_f, const float* __restrict__ Whh_b,
                             const float* __restrict__ bih_f, const float* __restrict__ bhh_f,
                             const float* __restrict__ bih_b, const float* __restrict__ bhh_b,
                             uint4* __restrict__ qWf, uint4* __restrict__ qWb,
                             float* __restrict__ scf, float* __restrict__ scb,
                             float* __restrict__ biasf, float* __restrict__ biasb,
                             const int* __restrict__ sents, const float* __restrict__ mask,
                             const float* __restrict__ emb, float* __restrict__ embeds,
                             float* __restrict__ out) {
    int tid = threadIdx.x;
    if (blockIdx.x < 512) {
        int bl = blockIdx.x;
        const int*   srow = sents + bl*32;
        const float* mrow = mask  + bl*32;
        float acc = 0.0f, el = 0.0f;
        for (int w = 0; w < 32; ++w) {
            float m = mrow[w];
            el  += m;
            acc += emb[(size_t)srow[w]*256 + tid] * m;
        }
        float den = el + (el == 0.0f ? 1.0f : 0.0f);
        embeds[bl*256 + tid] = acc / den;
        if (bl == 0)      { for (int q = tid; q < 1024; q += 256) biasf[q] = bih_f[q] + bhh_f[q]; }
        else if (bl == 1) { for (int q = tid; q < 1024; q += 256) biasb[q] = bih_b[q] + bhh_b[q]; }
        else if (bl == 2 && tid == 0) out[0] = 0.0f;
    } else {
        int pb  = blockIdx.x - 512;      // 0..127
        int dir = pb >> 6;
        int cg  = pb & 63;               // cell group of 4
        const float* W = dir ? Whh_b : Whh_f;
        uint4* qW = dir ? qWb : qWf;
        float* sc = dir ? scb : scf;
        __shared__ float Wl[16][260];    // 16 rows (4 gates x 4 cells), padded
        __shared__ float sL[16];         // row scales [g*4+jj]
        #pragma unroll
        for (int lr = 0; lr < 16; ++lr) {
            int g = lr >> 2, jj = lr & 3;
            int rowid = g*256 + cg*4 + jj;
            Wl[lr][tid] = W[(size_t)rowid*256 + tid];
        }
        __syncthreads();
        if (tid < 64) {
            int lr = tid >> 2, sub = tid & 3;
            float mx = 0.0f;
            for (int m = 0; m < 64; ++m) mx = fmaxf(mx, fabsf(Wl[lr][sub*64 + m]));
            mx = quad_max(mx);
            if (sub == 0) sL[lr] = mx * (1.0f/240.0f) + 1e-30f;
        }
        __syncthreads();
        int k4 = tid >> 2, jj = tid & 3;
        float is0 = 1.0f / sL[0*4 + jj];
        float is1 = 1.0f / sL[1*4 + jj];
        float is2 = 1.0f / sL[2*4 + jj];
        float is3 = 1.0f / sL[3*4 + jj];
        uint4 q;
        unsigned int* qq = (unsigned int*)&q;
        #pragma unroll
        for (int kk = 0; kk < 4; ++kk) {
            int k = k4*4 + kk;
            int d = 0;
            d = __builtin_amdgcn_cvt_pk_fp8_f32(Wl[0*4+jj][k]*is0, Wl[1*4+jj][k]*is1, d, false);
            d = __builtin_amdgcn_cvt_pk_fp8_f32(Wl[2*4+jj][k]*is2, Wl[3*4+jj][k]*is3, d, true);
            qq[kk] = (unsigned int)d;
        }
        qW[k4*256 + cg*4 + jj] = q;
        if (tid < 16) {
            int g = tid >> 2, j2 = tid & 3;
            sc[(cg*4 + j2)*4 + g] = sL[g*4 + j2];
        }
    }
}

// ---------------------------------------------------------------- 64x64 GEMM body, 4x4 micro-tile
// Keep for gemm_ih: round-11 measured the 32-tile variant REGRESSING ~7 us
// there ("more blocks" only pays when blocks < CUs; gemm_ih has 256).
__device__ __forceinline__ void gemm64_body(const float* __restrict__ A,
                                            const float* __restrict__ Bm,
                                            const float* __restrict__ bias,
                                            float* __restrict__ C,
                                            int N, int K, int bx, int by) {
    __shared__ __align__(16) float As[32][68];
    __shared__ __align__(16) float Bs[32][68];
    int tid = threadIdx.x;
    int tx = tid & 15, ty = tid >> 4;
    int row0 = bx * 64, col0 = by * 64;
    float acc[4][4];
    #pragma unroll
    for (int r = 0; r < 4; ++r)
        #pragma unroll
        for (int c = 0; c < 4; ++c) acc[r][c] = 0.0f;
    int lr = tid >> 2;
    int lc = (tid & 3) * 8;
    for (int k0 = 0; k0 < K; k0 += 32) {
        float4 a0 = *(const float4*)(A  + (size_t)(row0+lr)*K + k0 + lc);
        float4 a1 = *(const float4*)(A  + (size_t)(row0+lr)*K + k0 + lc + 4);
        float4 b0 = *(const float4*)(Bm + (size_t)(col0+lr)*K + k0 + lc);
        float4 b1 = *(const float4*)(Bm + (size_t)(col0+lr)*K + k0 + lc + 4);
        As[lc  ][lr] = a0.x; As[lc+1][lr] = a0.y; As[lc+2][lr] = a0.z; As[lc+3][lr] = a0.w;
        As[lc+4][lr] = a1.x; As[lc+5][lr] = a1.y; As[lc+6][lr] = a1.z; As[lc+7][lr] = a1.w;
        Bs[lc  ][lr] = b0.x; Bs[lc+1][lr] = b0.y; Bs[lc+2][lr] = b0.z; Bs[lc+3][lr] = b0.w;
        Bs[lc+4][lr] = b1.x; Bs[lc+5][lr] = b1.y; Bs[lc+6][lr] = b1.z; Bs[lc+7][lr] = b1.w;
        __syncthreads();
        #pragma unroll
        for (int kc = 0; kc < 32; ++kc) {
            float4 xa = *(const float4*)&As[kc][ty*4];
            float4 xb = *(const float4*)&Bs[kc][tx*4];
            acc[0][0] = fmaf(xa.x, xb.x, acc[0][0]);
            acc[0][1] = fmaf(xa.x, xb.y, acc[0][1]);
            acc[0][2] = fmaf(xa.x, xb.z, acc[0][2]);
            acc[0][3] = fmaf(xa.x, xb.w, acc[0][3]);
            acc[1][0] = fmaf(xa.y, xb.x, acc[1][0]);
            acc[1][1] = fmaf(xa.y, xb.y, acc[1][1]);
            acc[1][2] = fmaf(xa.y, xb.z, acc[1][2]);
            acc[1][3] = fmaf(xa.y, xb.w, acc[1][3]);
            acc[2][0] = fmaf(xa.z, xb.x, acc[2][0]);
            acc[2][1] = fmaf(xa.z, xb.y, acc[2][1]);
            acc[2][2] = fmaf(xa.z, xb.z, acc[2][2]);
            acc[2][3] = fmaf(xa.z, xb.w, acc[2][3]);
            acc[3][0] = fmaf(xa.w, xb.x, acc[3][0]);
            acc[3][1] = fmaf(xa.w, xb.y, acc[3][1]);
            acc[3][2] = fmaf(xa.w, xb.z, acc[3][2]);
            acc[3][3] = fmaf(xa.w, xb.w, acc[3][3]);
        }
        __syncthreads();
    }
    float4 bv = bias ? *(const float4*)&bias[col0 + tx*4] : make_float4(0.f,0.f,0.f,0.f);
    #pragma unroll
    for (int r = 0; r < 4; ++r) {
        float4 o;
        o.x = acc[r][0] + bv.x; o.y = acc[r][1] + bv.y;
        o.z = acc[r][2] + bv.z; o.w = acc[r][3] + bv.w;
        *(float4*)(C + (size_t)(row0 + ty*4 + r)*N + col0 + tx*4) = o;
    }
}

// ---------------------------------------------------------------- 32x32 GEMM body, 2x2 micro-tile (p1/p2 only)
__device__ __forceinline__ void gemm32_body(const float* __restrict__ A,
                                            const float* __restrict__ Bm,
                                            const float* __restrict__ bias,
                                            float* __restrict__ C,
                                            int N, int K, int bx, int by) {
    __shared__ __align__(16) float As[32][36];
    __shared__ __align__(16) float Bs[32][36];
    int tid = threadIdx.x;
    int tx = tid & 15, ty = tid >> 4;
    int row0 = bx * 32, col0 = by * 32;
    float acc00 = 0.f, acc01 = 0.f, acc10 = 0.f, acc11 = 0.f;
    int lr = tid >> 3;            // 0..31
    int lc = (tid & 7) * 4;       // 0..28
    for (int k0 = 0; k0 < K; k0 += 32) {
        float4 a0 = *(const float4*)(A  + (size_t)(row0+lr)*K + k0 + lc);
        float4 b0 = *(const float4*)(Bm + (size_t)(col0+lr)*K + k0 + lc);
        As[lc  ][lr] = a0.x; As[lc+1][lr] = a0.y; As[lc+2][lr] = a0.z; As[lc+3][lr] = a0.w;
        Bs[lc  ][lr] = b0.x; Bs[lc+1][lr] = b0.y; Bs[lc+2][lr] = b0.z; Bs[lc+3][lr] = b0.w;
        __syncthreads();
        #pragma unroll
        for (int kc = 0; kc < 32; ++kc) {
            float2 xa = *(const float2*)&As[kc][ty*2];
            float2 xb = *(const float2*)&Bs[kc][tx*2];
            acc00 = fmaf(xa.x, xb.x, acc00);
            acc01 = fmaf(xa.x, xb.y, acc01);
            acc10 = fmaf(xa.y, xb.x, acc10);
            acc11 = fmaf(xa.y, xb.y, acc11);
        }
        __syncthreads();
    }
    float2 bv = *(const float2*)&bias[col0 + tx*2];
    float2 o0; o0.x = acc00 + bv.x; o0.y = acc01 + bv.y;
    float2 o1; o1.x = acc10 + bv.x; o1.y = acc11 + bv.y;
    *(float2*)(C + (size_t)(row0 + ty*2    )*N + col0 + tx*2) = o0;
    *(float2*)(C + (size_t)(row0 + ty*2 + 1)*N + col0 + tx*2) = o1;
}

__global__ __launch_bounds__(256) void gemm_ih(const float* __restrict__ embeds,
                                               const float* __restrict__ Wf, const float* __restrict__ Wb,
                                               const float* __restrict__ biasf, const float* __restrict__ biasb,
                                               float* __restrict__ gxf, float* __restrict__ gxb) {
    int dir = blockIdx.z;
    gemm64_body(embeds, dir ? Wb : Wf, dir ? biasb : biasf, dir ? gxb : gxf,
                1024, 256, blockIdx.x, blockIdx.y);
}

// ---------------------------------------------------------------- LSTM recurrence (fp8 weights, 2-way K split)
__global__ __launch_bounds__(512) void lstm_rec(const float* __restrict__ gxf,
                                                const float* __restrict__ gxb,
                                                const uint4* __restrict__ qWf,
                                                const uint4* __restrict__ qWb,
                                                const float* __restrict__ scf,
                                                const float* __restrict__ scb,
                                                float* __restrict__ hall) {
    int blk  = blockIdx.x;        // 0..255: (rep, dir, pos)
    int rep  = blk >> 7;
    blk &= 127;
    int dir  = blk >> 6;
    int pos  = blk & 63;
    int tid  = threadIdx.x;
    int j    = tid & 255;         // cell
    int half = tid >> 8;          // K half
    const float* gx = dir ? gxb : gxf;
    const uint4* qW = dir ? qWb : qWf;
    float4 sc = ((const float4*)(dir ? scb : scf))[j];
    __shared__ __align__(16) float hs[256];
    __shared__ __align__(16) float part[256][4];
    if (tid < 256) hs[tid] = 0.0f;
    float cellc = 0.0f;
    __syncthreads();
    const uint4* qWh = qW + (half << 13);       // + half*32*256
    const float* hsh = hs + (half << 7);        // + half*32*4
    for (int s = 0; s < 8; ++s) {
        int t = dir ? (7 - s) : s;
        const float* g0 = gx + (size_t)(t*64 + pos)*1024;
        float ai = 0.0f, af = 0.0f, ag = 0.0f, ao = 0.0f;
        if (half == 0) { ai = g0[j]; af = g0[256+j]; ag = g0[512+j]; ao = g0[768+j]; }
        float qi = 0.0f, qf = 0.0f, qg = 0.0f, qo = 0.0f;
        #pragma unroll 8
        for (int k4 = 0; k4 < 32; ++k4) {
            uint4 wq = qWh[(k4 << 8) + j];
            float4 hp = *(const float4*)&hsh[k4*4];
            floatx2 pa, pb;
            pa = __builtin_amdgcn_cvt_pk_f32_fp8(wq.x, false);
            pb = __builtin_amdgcn_cvt_pk_f32_fp8(wq.x, true);
            qi = fmaf(pa.x, hp.x, qi); qf = fmaf(pa.y, hp.x, qf);
            qg = fmaf(pb.x, hp.x, qg); qo = fmaf(pb.y, hp.x, qo);
            pa = __builtin_amdgcn_cvt_pk_f32_fp8(wq.y, false);
            pb = __builtin_amdgcn_cvt_pk_f32_fp8(wq.y, true);
            qi = fmaf(pa.x, hp.y, qi); qf = fmaf(pa.y, hp.y, qf);
            qg = fmaf(pb.x, hp.y, qg); qo = fmaf(pb.y, hp.y, qo);
            pa = __builtin_amdgcn_cvt_pk_f32_fp8(wq.z, false);
            pb = __builtin_amdgcn_cvt_pk_f32_fp8(wq.z, true);
            qi = fmaf(pa.x, hp.z, qi); qf = fmaf(pa.y, hp.z, qf);
            qg = fmaf(pb.x, hp.z, qg); qo = fmaf(pb.y, hp.z, qo);
            pa = __builtin_amdgcn_cvt_pk_f32_fp8(wq.w, false);
            pb = __builtin_amdgcn_cvt_pk_f32_fp8(wq.w, true);
            qi = fmaf(pa.x, hp.w, qi); qf = fmaf(pa.y, hp.w, qf);
            qg = fmaf(pb.x, hp.w, qg); qo = fmaf(pb.y, hp.w, qo);
        }
        if (half) { part[j][0] = qi; part[j][1] = qf; part[j][2] = qg; part[j][3] = qo; }
        __syncthreads();
        if (half == 0) {
            float4 pr = *(const float4*)&part[j][0];
            ai = fmaf(sc.x, qi + pr.x, ai);
            af = fmaf(sc.y, qf + pr.y, af);
            ag = fmaf(sc.z, qg + pr.z, ag);
            ao = fmaf(sc.w, qo + pr.w, ao);
            cellc = sigf(af)*cellc + sigf(ai)*tanhf(ag);
            float h0 = sigf(ao)*tanhf(cellc);
            hs[j] = h0;
            if (rep == 0) hall[(size_t)(t*64 + pos)*512 + dir*256 + j] = h0;
        }
        __syncthreads();
    }
}

// ---------------------------------------------------------------- uv + p1 + p2 fused
__global__ __launch_bounds__(256) void post_lstm(const float* __restrict__ hall,
                                                 const float* __restrict__ Ws,
                                                 float* __restrict__ u, float* __restrict__ v,
                                                 const float* __restrict__ W1, const float* __restrict__ b1,
                                                 const float* __restrict__ W2, const float* __restrict__ b2,
                                                 float* __restrict__ p1, float* __restrict__ p2) {
    if (blockIdx.x < 512) {
        int bi = blockIdx.x;
        int i  = bi & 63;
        int tid = threadIdx.x;
        float pu = 0.0f, pv = 0.0f;
        for (int q = tid; q < 1536; q += 256) {
            int seg = q >> 9, kk = q & 511;
            float tv = 0.0f;
            if (seg == 0)       tv = hall[(size_t)bi*512 + kk];
            else if (seg == 1)  { if (i > 0)  tv = hall[(size_t)(bi-1)*512 + kk]; }
            else                { if (i < 63) tv = hall[(size_t)(bi+1)*512 + kk]; }
            pu = fmaf(tv, Ws[q],        pu);
            pv = fmaf(tv, Ws[1536 + q], pv);
        }
        for (int off = 32; off; off >>= 1) { pu += __shfl_xor(pu, off); pv += __shfl_xor(pv, off); }
        __shared__ float ru[4], rv[4];
        int wv = tid >> 6, lane = tid & 63;
        if (lane == 0) { ru[wv] = pu; rv[wv] = pv; }
        __syncthreads();
        if (tid == 0) { u[bi] = ru[0]+ru[1]+ru[2]+ru[3]; v[bi] = rv[0]+rv[1]+rv[2]+rv[3]; }
    } else {
        int gb = blockIdx.x - 512;         // 0..127
        int sel = gb >> 6; gb &= 63;       // 64 tiles per matrix: 16 row x 4 col
        gemm32_body(hall, sel ? W2 : W1, sel ? b2 : b1, sel ? p2 : p1,
                    128, 512, gb >> 2, gb & 3);
    }
}

// ---------------------------------------------------------------- Eisner + fused S-GEMM + finalize
// 512 threads/block; 256 blocks = 32 replicas x 8 batches (replica 0 commits).
// ROUND-13: LINEAR-DOMAIN DP. Tables store E = 2^(L - 2*width) (L = value in
// log2 units). LSE-of-sums becomes dot products: s1 = sum T1[i][k]*T2[j][k]
// etc. -- the fmax tree, oct_max, 36 exp2 and 3 log2 per level all vanish.
// Scale 2/width ~ measured tree-count growth (logZ ~ 126 log2 / 63 widths);
// growth log2(3+2*sqrt(2)) ~ 2.54 < 4 -> products can't overflow fp32;
// deviations bound values in ~[2^-15, 2^5] -> no underflow.
// Masks ALSO vanish: for every out-of-range k, at least one product factor
// is a not-yet-written (future-level or impossible) slot = 0 in the
// zero-initialized tables (case-checked incl. same-level benign races).
// Updates: Ir~ = 0.25*s1*eDr (width-sum of va pairs is w-1 -> 2^-2 factor);
// Cr~ = sr + Ir~; Cl~ = sl + Il~. Seeds: T1[d][d]=1, T2[d][d-1]=1, rest 0.
// logZ = (log2(T1[0][63]) + 126)*ln2.
// Prior attempts (do not re-add): reg-mirror (r8, not LDS-bound), 1024-thr
// (r5, issue growth). Phase A k4 loop: unroll 2 pragma is load-bearing --
// full unroll spilled 174 MB scratch (r1-2).
__global__ __launch_bounds__(512, 2) void eisner_final(const float* __restrict__ u,
                                                    const float* __restrict__ v,
                                                    const float* __restrict__ bs,
                                                    const float* __restrict__ p1,
                                                    const float* __restrict__ p2,
                                                    const float* __restrict__ prior,
                                                    const int* __restrict__ heads,
                                                    float* __restrict__ out) {
    int b   = blockIdx.x & 7;
    int rep = blockIdx.x >> 3;
    __shared__ __align__(16) float SMEM[3*64*TSTRIDE + 64];   // DP tables / stage / Sl (time-shared)
    __shared__ float su[64], sv[64], lseSb[64], sBest[1];
    float* T1 = &SMEM[0];
    float* T2 = &SMEM[64*TSTRIDE];
    float* T3 = &SMEM[2*64*TSTRIDE];
    int tid = threadIdx.x;
    float bsv = bs[0];
    if (tid < 64) {
        su[tid] = u[b*64 + tid];
        sv[tid] = v[b*64 + tid];
    }
    // ---- Phase A: S = p1[b] @ p2[b]^T (64x64x128), two K-halves through LDS
    const float4* g1 = (const float4*)(p1 + (size_t)b*8192);
    const float4* g2 = (const float4*)(p2 + (size_t)b*8192);
    float4* s1p = (float4*)SMEM;                   // 64 rows x 17 float4 (stride 68 floats)
    float4* s2p = (float4*)(SMEM + 64*TSTRIDE);
    int r   = tid >> 3;                            // output row / span index
    int sub = tid & 7;
    float acc[8];                                  // acc[q] = S[r][sub + 8q]
    #pragma unroll
    for (int q = 0; q < 8; ++q) acc[q] = 0.0f;
    for (int p = 0; p < 2; ++p) {
        #pragma unroll
        for (int f0 = 0; f0 < 4; ++f0) {
            int f = f0*512 + tid;
            int half = f >> 10;                    // 0: p1, 1: p2
            int ff = f & 1023;
            int row = ff >> 4, c4 = ff & 15;
            float4 vv = (half ? g2 : g1)[row*32 + (p<<4) + c4];
            (half ? s2p : s1p)[row*17 + c4] = vv;
        }
        __syncthreads();
        #pragma unroll 2
        for (int k4 = 0; k4 < 16; ++k4) {
            float4 a = s1p[r*17 + k4];
            #pragma unroll
            for (int q = 0; q < 8; ++q) {
                float4 bv = s2p[(sub + (q<<3))*17 + k4];
                acc[q] = fmaf(a.x, bv.x, acc[q]);
                acc[q] = fmaf(a.y, bv.y, acc[q]);
                acc[q] = fmaf(a.z, bv.z, acc[q]);
                acc[q] = fmaf(a.w, bv.w, acc[q]);
            }
        }
        __syncthreads();
    }
    // row-LSE of S straight from registers (8 lanes own a row)
    float pm = acc[0];
    #pragma unroll
    for (int q = 1; q < 8; ++q) pm = fmaxf(pm, acc[q]);
    pm = fmaxf(pm, __int_as_float(__builtin_amdgcn_mov_dpp(__float_as_int(pm), 0xB1, 0xF, 0xF, true)));
    pm = fmaxf(pm, __int_as_float(__builtin_amdgcn_mov_dpp(__float_as_int(pm), 0x4E, 0xF, 0xF, true)));
    pm = fmaxf(pm, __int_as_float(__builtin_amdgcn_mov_dpp(__float_as_int(pm), 0x141, 0xF, 0xF, true)));
    float ps = 0.0f;
    #pragma unroll
    for (int q = 0; q < 8; ++q) ps += exp2f((acc[q] - pm) * L2E);
    ps = oct_sum(ps);
    if (sub == 0) lseSb[r] = pm + log2f(ps) * LN2;
    // dump S into recycled stage LDS (stride 66)
    float* Sl = SMEM;
    #pragma unroll
    for (int q = 0; q < 8; ++q) Sl[r*66 + sub + (q<<3)] = acc[q];
    __syncthreads();
    // gold-arc score (wave 0 only), before the DP recycles Sl's LDS
    if (tid < 64) {
        int m = tid;
        float gv = -INFINITY;
        if (m >= 1) {
            int hd = heads[b*64 + m];
            gv = su[hd] + sv[m] + bsv + (Sl[hd*66 + m] - lseSb[hd])
               + prior[(size_t)(b*64 + hd)*64 + m] * (1.0f/64.0f);
        }
        float mm = gv;
        for (int off = 32; off; off >>= 1) mm = fmaxf(mm, __shfl_xor(mm, off));
        float se = (m >= 1) ? exp2f((gv - mm) * L2E) : 0.0f;
        for (int off = 32; off; off >>= 1) se += __shfl_xor(se, off);
        if (m == 0) sBest[0] = mm + log2f(se) * LN2;
    }
    __syncthreads();
    // ---- Phase B: zero tables (zero = "no entry" in linear domain) + seeds
    for (int q = tid; q < 3*64*TSTRIDE; q += 512) SMEM[q] = 0.0f;
    __syncthreads();
    if (tid < 64) {
        T1[tid*TSTRIDE + tid] = 1.0f;              // C_r[d][d] = 0 nats
        if (tid >= 1) T2[tid*TSTRIDE + tid-1] = 1.0f;  // C_l[d][d] (shifted slot)
    }
    __syncthreads();
    int i = r;
    int k0 = i & ~3;
    float sui_b = su[i] + bsv;
    float svi_b = sv[i] + bsv;
    const float* t1i = &T1[i*TSTRIDE];
    const float* t2i = &T2[i*TSTRIDE];
    const float* t3i = &T3[i*TSTRIDE];
    for (int w = 1; w < 64; ++w) {
        int ns = 64 - w;
        if (i < ns) {
            int j = i + w;
            const float* t1j = &T1[j*TSTRIDE];
            const float* t2j = &T2[j*TSTRIDE];
            const float* t3j = &T3[j*TSTRIDE];
            float eDr = exp2f((sui_b + sv[j]) * L2E);
            float eDl = exp2f((su[j] + svi_b) * L2E);
            float s1 = 0.0f, sr = 0.0f, sl = 0.0f;
            #pragma unroll
            for (int t = 0; t < 2; ++t) {
                int k = k0 + ((t << 3) + sub) * 4;
                if (k < j) {
                    float4 a1  = *(const float4*)&t1i[k];
                    float4 b1  = *(const float4*)&t2j[k];
                    float4 a2  = *(const float4*)&t3i[k];
                    float4 b2v = *(const float4*)&t1j[k];
                    float4 a3  = *(const float4*)&t2i[k];
                    float4 b3  = *(const float4*)&t3j[k];
                    #pragma unroll
                    for (int c = 0; c < 4; ++c) {
                        s1 = fmaf(((const float*)&a1)[c], ((const float*)&b1)[c],  s1);
                        sr = fmaf(((const float*)&a2)[c], ((const float*)&b2v)[c], sr);
                        sl = fmaf(((const float*)&a3)[c], ((const float*)&b3)[c],  sl);
                    }
                }
            }
            s1 = oct_sum(s1);
            sr = oct_sum(sr);
            sl = oct_sum(sl);
            if (sub == 0) {
                float Ir = 0.25f * s1 * eDr;       // va width-sum = w-1 -> 2^-2
                float Il = 0.25f * s1 * eDl;
                float Cr = sr + Ir;
                float Cl = sl + Il;
                T3[i*TSTRIDE + j] = Ir;
                T1[i*TSTRIDE + j] = Cr;
                T1[j*TSTRIDE + i] = Cr;
                T3[j*TSTRIDE + i] = Il;
                T2[i*TSTRIDE + j] = Cl;
                if (i >= 1) T2[j*TSTRIDE + i-1] = Cl;
            }
        }
        __syncthreads();
    }
    if (rep == 0 && tid == 0) {
        float logZv = (log2f(T1[0*TSTRIDE + 63]) + 126.0f) * LN2;
        atomicAdd(out, -(sBest[0] - logZv) * 0.125f);
    }
}

// ---------------------------------------------------------------- launch
extern "C" void kernel_launch(void* const* d_in, const int* in_sizes, int n_in,
                              void* d_out, int out_size, void* d_ws, size_t ws_size,
                              hipStream_t stream) {
    const int*   sents = (const int*)  d_in[0];
    const float* mask  = (const float*)d_in[1];
    const float* prior = (const float*)d_in[2];
    const int*   heads = (const int*)  d_in[3];
    const float* emb   = (const float*)d_in[4];
    const float* Wih_f = (const float*)d_in[5];
    const float* Whh_f = (const float*)d_in[6];
    const float* bih_f = (const float*)d_in[7];
    const float* bhh_f = (const float*)d_in[8];
    const float* Wih_b = (const float*)d_in[9];
    const float* Whh_b = (const float*)d_in[10];
    const float* bih_b = (const float*)d_in[11];
    const float* bhh_b = (const float*)d_in[12];
    const float* W1    = (const float*)d_in[13];
    const float* b1    = (const float*)d_in[14];
    const float* W2    = (const float*)d_in[15];
    const float* b2    = (const float*)d_in[16];
    const float* Ws    = (const float*)d_in[17];
    const float* bs    = (const float*)d_in[18];
    float* out = (float*)d_out;

    char* w = (char*)d_ws;
    float* embeds = (float*)(w + 0);                 // 512 KB
    float* gxf    = (float*)(w + 524288);            // 2 MB
    float* gxb    = (float*)(w + 2621440);           // 2 MB
    uint4* qWf    = (uint4*)(w + 4718592);           // 256 KB
    uint4* qWb    = (uint4*)(w + 4980736);           // 256 KB
    float* scf    = (float*)(w + 5242880);           // 4 KB
    float* scb    = (float*)(w + 5246976);           // 4 KB
    float* biasf  = (float*)(w + 5767168);           // 4 KB
    float* biasb  = (float*)(w + 5771264);           // 4 KB
    float* hall   = (float*)(w + 5775360);           // 1 MB
    float* uArr   = (float*)(w + 6823936);
    float* vArr   = (float*)(w + 6825984);
    float* p1     = (float*)(w + 6828032);
    float* p2     = (float*)(w + 7090176);

    prep_all<<<640, 256, 0, stream>>>(Whh_f, Whh_b, bih_f, bhh_f, bih_b, bhh_b,
                                      qWf, qWb, scf, scb, biasf, biasb,
                                      sents, mask, emb, embeds, out);
    gemm_ih<<<dim3(8,16,2), 256, 0, stream>>>(embeds, Wih_f, Wih_b, biasf, biasb, gxf, gxb);
    lstm_rec<<<256, 512, 0, stream>>>(gxf, gxb, qWf, qWb, scf, scb, hall);
    post_lstm<<<640, 256, 0, stream>>>(hall, Ws, uArr, vArr, W1, b1, W2, b2, p1, p2);
    eisner_final<<<256, 512, 0, stream>>>(uArr, vArr, bs, p1, p2, prior, heads, out);
    (void)in_sizes; (void)n_in; (void)out_size; (void)ws_size;
}